// Round 10
// baseline (358.115 us; speedup 1.0000x reference)
//
#include <hip/hip_runtime.h>
#include <hip/hip_bf16.h>
#include <stdint.h>

// Problem constants
#define Bq 8
#define Lq 2048
#define Dq 1024
#define Pq 4
#define Kq 4096          // D*P
#define LPAD 2056        // 3 zero rows + 2048 data + 5 slack, per batch
// GEMM tiling: 256x256, BK=64, 8 waves, 2-phase/K-tile, CROSS-PHASE READ-AHEAD
// (phase issues next phase's ds_reads, MFMAs current set -> LDS || MFMA overlap)
#define BM 256
#define BN 256
#define BK 64

typedef __attribute__((ext_vector_type(8))) short short8;   // 8 bf16 (4 VGPRs)
typedef __attribute__((ext_vector_type(4))) float f32x4;

__device__ __forceinline__ unsigned short f2bf(float f) {
  unsigned u = __float_as_uint(f);
  u += 0x7FFFu + ((u >> 16) & 1u);   // round-to-nearest-even
  return (unsigned short)(u >> 16);
}

__device__ __forceinline__ void gload_lds16(const void* g, void* l) {
  __builtin_amdgcn_global_load_lds(
      (const __attribute__((address_space(1))) void*)g,
      (__attribute__((address_space(3))) void*)l, 16, 0, 0);
}

// ---- merged prep: blocks [0,8224) do xp, blocks [8224,10272) do Wp ----
__global__ void k_prep(const float* __restrict__ x, const float* __restrict__ W,
                       unsigned short* __restrict__ xp, unsigned short* __restrict__ Wp) {
  if (blockIdx.x < 8224u) {
    unsigned g = blockIdx.x * blockDim.x + threadIdx.x;
    unsigned base = g * 8;
    const unsigned total = (unsigned)Bq * LPAD * Dq;
    if (base >= total) return;
    unsigned t = base >> 10;            // b*LPAD + r
    unsigned b = t / LPAD;
    unsigned r = t - b * LPAD;
    unsigned d = base & 1023;
    short8 o;
    if (r >= 3 && r < 3 + Lq) {
      const float* s = x + ((size_t)b * Lq + (r - 3)) * Dq + d;
      float4 v0 = *(const float4*)(s);
      float4 v1 = *(const float4*)(s + 4);
      o[0] = (short)f2bf(v0.x); o[1] = (short)f2bf(v0.y);
      o[2] = (short)f2bf(v0.z); o[3] = (short)f2bf(v0.w);
      o[4] = (short)f2bf(v1.x); o[5] = (short)f2bf(v1.y);
      o[6] = (short)f2bf(v1.z); o[7] = (short)f2bf(v1.w);
    } else {
      o = (short8)0;
    }
    *(short8*)(xp + base) = o;
  } else {
    unsigned g = (blockIdx.x - 8224u) * blockDim.x + threadIdx.x;
    unsigned base = g * 8;
    unsigned d = base >> 12;
    unsigned rem = base & 4095;
    unsigned dp = rem >> 2;                               // even
    const float4* src = (const float4*)(W + base);
    float4 v0 = src[0];
    float4 v1 = src[1];
    float a0[4] = {v0.x, v0.y, v0.z, v0.w};
    float a1[4] = {v1.x, v1.y, v1.z, v1.w};
#pragma unroll
    for (int i = 0; i < 4; ++i) {
      unsigned packed = (unsigned)f2bf(a0[i]) | ((unsigned)f2bf(a1[i]) << 16);
      *(unsigned*)(Wp + (size_t)d * 4096 + (size_t)i * 1024 + dp) = packed;
    }
  }
}

// ====== 256x256 GEMM, 2-phase/K-tile, cross-phase read-ahead ======
// C[m][n] = sum_k A[m][k]*Wp[n][k] + bias[n],  A[m][i*1024+d'] = xp[b][l+3-i][d']
// LDS (128 KiB): A in [0,64K): [buf:32K][h:16K]; B in [64K,128K): same.
//   byte within 128B row: SWIZZLED  phys_c = log_c ^ ((r&7)<<4)
// 8 waves: wm = w>>2, wn = w&3.
// Fragment sets: a0,a1 (A halves), bXe/bYe (B of even tile), bXo/bYo (odd).
// Phase p issues ds_reads for phase p+1's MFMA set, then MFMAs the current
// set (no dependency -> MFMA issues while LDS serves reads).
// Per tile pair T (even, buf0), U=T+1 (odd, buf1):
//  phA(T): rd a1<-A1(T,b0);           st A1(U)->b1;           MFMA(a0,bXe,bYe Q0*); VM2; BAR
//  phB(T): rd a0,bXo,bYo<-A0,B0,B1(U,b1); st A0B0B1(T+2)->b0; MFMA(a1,bXe,bYe Q1*); VM6; BAR
//  phA(U): rd a1<-A1(U,b1);           st A1(T+2)->b0;         MFMA(a0,bXo,bYo Q0*); VM2; BAR
//  phB(U): rd a0,bXe,bYe<-tile T+2,b0;   st A0B0B1(T+3)->b1;  MFMA(a1,bXo,bYo Q1*); VM6; BAR
// vmcnt ledger: VM2 leaves phA's own 2 stages; VM6 leaves phB's own 6 ->
// every read's data is drained >=1 phase before use (incl. prologue/epilogue).
// Write-after-read: each stage lands >=1 barrier after its region's reads
// completed (reads consumed by prior phase's MFMA via lgkm before BAR).

#define VM6 asm volatile("s_waitcnt vmcnt(6)" ::: "memory")
#define VM2 asm volatile("s_waitcnt vmcnt(2)" ::: "memory")
#define VM0 asm volatile("s_waitcnt vmcnt(0)" ::: "memory")
#define BAR __builtin_amdgcn_s_barrier()

#define STAGE_A(buf, kt, h) do { \
    const unsigned scl_ = ((((unsigned)(bRow0 + (h) * 64 - ((kt) >> 4))) << 10) + (((unsigned)(kt) & 15u) << 6)) << 1; \
    _Pragma("unroll") for (int q_ = 0; q_ < 2; ++q_) \
      gload_lds16((const char*)xp + (thrA[q_] + scl_), \
                  lds + ((buf) << 15) + ((h) << 14) + (q_ << 13) + (tid << 4)); \
  } while (0)

#define STAGE_B(buf, kt, h) do { \
    const unsigned scl_ = ((((unsigned)(n0 + (h) * 32)) << 12) + ((unsigned)(kt) << 6)) << 1; \
    _Pragma("unroll") for (int q_ = 0; q_ < 2; ++q_) \
      gload_lds16((const char*)Wp + (thrB[q_] + scl_), \
                  lds + 65536 + ((buf) << 15) + ((h) << 14) + (q_ << 13) + (tid << 4)); \
  } while (0)

#define READ_A(dst, buf, h) do { \
    _Pragma("unroll") for (int mi = 0; mi < 4; ++mi) \
    _Pragma("unroll") for (int kk = 0; kk < 2; ++kk) \
      dst[mi][kk] = *(const short8*)(lds + (((buf) << 15) + ((h) << 14)) + aRC[mi][kk]); \
  } while (0)

#define READ_B(dst, buf, h) do { \
    _Pragma("unroll") for (int ni = 0; ni < 2; ++ni) \
    _Pragma("unroll") for (int kk = 0; kk < 2; ++kk) \
      dst[ni][kk] = *(const short8*)(lds + (((buf) << 15) + ((h) << 14)) + bRC[ni][kk]); \
  } while (0)

// 32 MFMA covering quadrants (mh,0..3), kk-outer (dep distance 16)
#define MFMA_PAIR(mh, A, BX, BY) do { \
    __builtin_amdgcn_s_setprio(1); \
    _Pragma("unroll") for (int kk = 0; kk < 2; ++kk) { \
      _Pragma("unroll") for (int mi = 0; mi < 4; ++mi) \
      _Pragma("unroll") for (int ni = 0; ni < 2; ++ni) \
        acc[(mh) * 4 + mi][ni] = __builtin_amdgcn_mfma_f32_16x16x32_bf16( \
            A[mi][kk], BX[ni][kk], acc[(mh) * 4 + mi][ni], 0, 0, 0); \
      _Pragma("unroll") for (int mi = 0; mi < 4; ++mi) \
      _Pragma("unroll") for (int ni = 0; ni < 2; ++ni) \
        acc[(mh) * 4 + mi][2 + ni] = __builtin_amdgcn_mfma_f32_16x16x32_bf16( \
            A[mi][kk], BY[ni][kk], acc[(mh) * 4 + mi][2 + ni], 0, 0, 0); \
    } \
    __builtin_amdgcn_s_setprio(0); \
  } while (0)

__global__ void __launch_bounds__(512, 1)
k_gemm(const unsigned short* __restrict__ xp,
       const unsigned short* __restrict__ Wp,
       const float* __restrict__ bias,
       float* __restrict__ out) {
  __shared__ __attribute__((aligned(16))) unsigned char lds[131072];

  const int tid  = threadIdx.x;
  const int lane = tid & 63;
  const int w    = tid >> 6;       // 0..7
  const int wm   = w >> 2;         // 0..1
  const int wn   = w & 3;          // 0..3

  // bijective XCD swizzle (256 blocks): each XCD gets a contiguous
  // 8-mtile x 4-ntile chunk -> A fetched once per XCD.
  const int bid = blockIdx.x;
  const int swz = (bid & 7) * 32 + (bid >> 3);
  const int m0 = (swz >> 2) * BM;
  const int n0 = (swz & 3) * BN;
  const int b  = m0 >> 11;
  const int l0 = m0 & 2047;
  const int bRow0 = b * LPAD + l0 + 3;           // SGPR

  // ---- staging geometry: per-thread u32 BYTE offsets (invariant part) ----
  const int sr0 = tid >> 3;                                  // 0..63
  const unsigned clog = ((unsigned)((tid & 7) ^ (sr0 & 7))) << 3;  // elem offset
  unsigned thrA[2], thrB[2];
  const unsigned nb0 = (((unsigned)sr0 >> 5) << 6) + ((unsigned)sr0 & 31);
#pragma unroll
  for (int q = 0; q < 2; ++q) {
    thrA[q] = ((((unsigned)(sr0 + q * 128)) << 10) + clog) << 1;   // bytes
    thrB[q] = (((nb0 + q * 128u) << 12) + clog) << 1;              // bytes
  }

  // ---- ds_read addresses: precomputed VGPRs, region via offset-imm ----
  int aRC[4][2], bRC[2][2];
  {
    int colByte[2];
#pragma unroll
    for (int kk = 0; kk < 2; ++kk)
      colByte[kk] = (kk * 64 + ((lane >> 4) << 4)) ^ ((lane & 7) << 4);
#pragma unroll
    for (int mi = 0; mi < 4; ++mi)
#pragma unroll
      for (int kk = 0; kk < 2; ++kk)
        aRC[mi][kk] = ((wm * 64 + mi * 16 + (lane & 15)) << 7) + colByte[kk];
#pragma unroll
    for (int ni = 0; ni < 2; ++ni)
#pragma unroll
      for (int kk = 0; kk < 2; ++kk)
        bRC[ni][kk] = 65536 + ((wn * 32 + ni * 16 + (lane & 15)) << 7) + colByte[kk];
  }

  f32x4 acc[8][4] = {};
  short8 a0[4][2], a1[4][2], bXe[2][2], bYe[2][2], bXo[2][2], bYo[2][2];

  // ---- prologue: T0 full + T1 (A0,B0,B1) = 14 gloads; preload tile0 frags ----
  STAGE_A(0, 0, 0);
  STAGE_B(0, 0, 0);
  STAGE_B(0, 0, 1);
  STAGE_A(0, 0, 1);
  STAGE_A(1, 1, 0);
  STAGE_B(1, 1, 0);
  STAGE_B(1, 1, 1);
  VM6;                               // g1..g8 landed (= tile0 complete)
  BAR;
  READ_A(a0, 0, 0); READ_B(bXe, 0, 0); READ_B(bYe, 0, 1);

  // ---- main loop: 31 iters, tiles T=2it (buf0), U=T+1 (buf1) ----
#pragma unroll 1
  for (int it = 0; it < 31; ++it) {
    const int T = it * 2;
    // phA(T)
    READ_A(a1, 0, 1);                          // A1(T)
    STAGE_A(1, T + 1, 1);
    MFMA_PAIR(0, a0, bXe, bYe);
    VM2; BAR;
    // phB(T)
    READ_A(a0, 1, 0); READ_B(bXo, 1, 0); READ_B(bYo, 1, 1);   // tile U
    STAGE_A(0, T + 2, 0); STAGE_B(0, T + 2, 0); STAGE_B(0, T + 2, 1);
    MFMA_PAIR(1, a1, bXe, bYe);
    VM6; BAR;
    // phA(U)
    READ_A(a1, 1, 1);                          // A1(U)
    STAGE_A(0, T + 2, 1);
    MFMA_PAIR(0, a0, bXo, bYo);
    VM2; BAR;
    // phB(U)
    READ_A(a0, 0, 0); READ_B(bXe, 0, 0); READ_B(bYe, 0, 1);   // tile T+2
    STAGE_A(1, T + 3, 0); STAGE_B(1, T + 3, 0); STAGE_B(1, T + 3, 1);
    MFMA_PAIR(1, a1, bXo, bYo);
    VM6; BAR;
  }

  // ---- epilogue: tiles 62 (buf0), 63 (buf1) ----
  // phA(62)
  READ_A(a1, 0, 1);
  STAGE_A(1, 63, 1);                 // last missing piece of tile 63
  MFMA_PAIR(0, a0, bXe, bYe);
  VM2; BAR;                          // A0,B0,B1(63) landed
  // phB(62)
  READ_A(a0, 1, 0); READ_B(bXo, 1, 0); READ_B(bYo, 1, 1);
  MFMA_PAIR(1, a1, bXe, bYe);
  VM0; BAR;                          // A1(63) landed
  // phA(63)
  READ_A(a1, 1, 1);
  MFMA_PAIR(0, a0, bXo, bYo);
  // phB(63)
  MFMA_PAIR(1, a1, bXo, bYo);

  // ---- C write: col = lane&15, row = (lane>>4)*4 + reg ----
#pragma unroll
  for (int nig = 0; nig < 4; ++nig) {
    const int col = n0 + wn * 64 + nig * 16 + (lane & 15);
    const float bv = bias[col];
#pragma unroll
    for (int mig = 0; mig < 8; ++mig) {
      const int row0 = m0 + wm * 128 + mig * 16 + ((lane >> 4) << 2);
#pragma unroll
      for (int t2 = 0; t2 < 4; ++t2)
        out[(size_t)(row0 + t2) * Dq + col] = acc[mig][nig][t2] + bv;
    }
  }
}

// ---- slow-but-correct fallback if workspace is too small ----
__global__ void k_naive(const float* __restrict__ x, const float* __restrict__ W,
                        const float* __restrict__ bias, float* __restrict__ out) {
  size_t g = (size_t)blockIdx.x * blockDim.x + threadIdx.x;
  const size_t total = (size_t)Bq * Lq * Dq;
  if (g >= total) return;
  int d = (int)(g & 1023);
  int l = (int)((g >> 10) & 2047);
  int b = (int)(g >> 21);
  float s = bias[d];
  for (int i = 0; i < Pq; ++i) {
    if (l - i < 0) continue;
    const float* xr = x + ((size_t)b * Lq + (l - i)) * Dq;
    const float* wr = W + (size_t)d * Kq + i;
    float accv = 0.f;
    for (int dp = 0; dp < Dq; ++dp) accv += xr[dp] * wr[(size_t)dp * 4];
    s += accv;
  }
  out[g] = s;
}

extern "C" void kernel_launch(void* const* d_in, const int* in_sizes, int n_in,
                              void* d_out, int out_size, void* d_ws, size_t ws_size,
                              hipStream_t stream) {
  const float* x    = (const float*)d_in[0];
  const float* W    = (const float*)d_in[1];
  const float* bias = (const float*)d_in[2];
  float* out = (float*)d_out;

  const size_t WP_BYTES = (size_t)Dq * Kq * sizeof(unsigned short);        // 8 MiB
  const size_t XP_BYTES = (size_t)Bq * LPAD * Dq * sizeof(unsigned short); // ~33.7 MB

  if (ws_size < WP_BYTES + XP_BYTES) {
    const size_t total = (size_t)Bq * Lq * Dq;
    k_naive<<<(unsigned)((total + 255) / 256), 256, 0, stream>>>(x, W, bias, out);
    return;
  }

  unsigned short* Wp = (unsigned short*)d_ws;
  unsigned short* xp = (unsigned short*)((char*)d_ws + WP_BYTES);

  k_prep<<<10272, 256, 0, stream>>>(x, W, xp, Wp);
  k_gemm<<<dim3((Bq * Lq / BM) * (Dq / BN)), 512, 0, stream>>>(xp, Wp, bias, out);
}

// Round 11
// 204.443 us; speedup vs baseline: 1.7517x; 1.7517x over previous
//
#include <hip/hip_runtime.h>
#include <hip/hip_bf16.h>
#include <stdint.h>

// Problem constants
#define Bq 8
#define Lq 2048
#define Dq 1024
#define Pq 4
#define Kq 4096          // D*P
#define LPAD 2056        // 3 zero rows + 2048 data + 5 slack, per batch
// GEMM tiling: 256x256, BK=64, 8 waves, 2-phase/K-tile,
// quadrant re-pairing + WAR-overwrite read-ahead (96 frag VGPRs).
#define BM 256
#define BN 256
#define BK 64

typedef __attribute__((ext_vector_type(8))) short short8;   // 8 bf16 (4 VGPRs)
typedef __attribute__((ext_vector_type(4))) float f32x4;

__device__ __forceinline__ unsigned short f2bf(float f) {
  unsigned u = __float_as_uint(f);
  u += 0x7FFFu + ((u >> 16) & 1u);   // round-to-nearest-even
  return (unsigned short)(u >> 16);
}

__device__ __forceinline__ void gload_lds16(const void* g, void* l) {
  __builtin_amdgcn_global_load_lds(
      (const __attribute__((address_space(1))) void*)g,
      (__attribute__((address_space(3))) void*)l, 16, 0, 0);
}

// ---- merged prep: blocks [0,8224) do xp, blocks [8224,10272) do Wp ----
__global__ void k_prep(const float* __restrict__ x, const float* __restrict__ W,
                       unsigned short* __restrict__ xp, unsigned short* __restrict__ Wp) {
  if (blockIdx.x < 8224u) {
    unsigned g = blockIdx.x * blockDim.x + threadIdx.x;
    unsigned base = g * 8;
    const unsigned total = (unsigned)Bq * LPAD * Dq;
    if (base >= total) return;
    unsigned t = base >> 10;            // b*LPAD + r
    unsigned b = t / LPAD;
    unsigned r = t - b * LPAD;
    unsigned d = base & 1023;
    short8 o;
    if (r >= 3 && r < 3 + Lq) {
      const float* s = x + ((size_t)b * Lq + (r - 3)) * Dq + d;
      float4 v0 = *(const float4*)(s);
      float4 v1 = *(const float4*)(s + 4);
      o[0] = (short)f2bf(v0.x); o[1] = (short)f2bf(v0.y);
      o[2] = (short)f2bf(v0.z); o[3] = (short)f2bf(v0.w);
      o[4] = (short)f2bf(v1.x); o[5] = (short)f2bf(v1.y);
      o[6] = (short)f2bf(v1.z); o[7] = (short)f2bf(v1.w);
    } else {
      o = (short8)0;
    }
    *(short8*)(xp + base) = o;
  } else {
    unsigned g = (blockIdx.x - 8224u) * blockDim.x + threadIdx.x;
    unsigned base = g * 8;
    unsigned d = base >> 12;
    unsigned rem = base & 4095;
    unsigned dp = rem >> 2;                               // even
    const float4* src = (const float4*)(W + base);
    float4 v0 = src[0];
    float4 v1 = src[1];
    float a0[4] = {v0.x, v0.y, v0.z, v0.w};
    float a1[4] = {v1.x, v1.y, v1.z, v1.w};
#pragma unroll
    for (int i = 0; i < 4; ++i) {
      unsigned packed = (unsigned)f2bf(a0[i]) | ((unsigned)f2bf(a1[i]) << 16);
      *(unsigned*)(Wp + (size_t)d * 4096 + (size_t)i * 1024 + dp) = packed;
    }
  }
}

// ====== 256x256 GEMM, quadrant re-pairing + WAR read-ahead ======
// C[m][n] = sum_k A[m][k]*Wp[n][k] + bias[n],  A[m][i*1024+d'] = xp[b][l+3-i][d']
// LDS (128 KiB): A in [0,64K): [buf:32K][h:16K]; B in [64K,128K): same.
//   byte within 128B row: SWIZZLED  phys_c = log_c ^ ((r&7)<<4)
// 8 waves: wm = w>>2, wn = w&3.
// Sets: a0 (A-half0, 32v), a1 (A-half1, 32v), bX (B0, 16v), bY (B1, 16v).
// Phase pairing: phA = Q00(a0,bX),Q01(a0,bY); phB = Q10(a1,bX),Q11(a1,bY).
// Read placement (all MFMA operands >= 1/2 phase old; zero in-phase deps):
//  phA(T): rd A1(T)->a1 (a1 dead in phA); st A0,B0(T+2); Q00,Q01; VM6; BAR
//  phB(T): rd A0(T+1)->a0 (a0 dead in phB); st B1,A1(T+2);
//          Q10; rd B0(T+1)->bX (WAR after Q10); Q11; rd B1(T+1)->bY; VM8; BAR
// vmcnt ledger (issue order per 2 phases = 4+4 gloads, 12-deep pipe):
//  VM6 after phA leaves {A1(next)x2 + this phA's 4}; VM8 after phB leaves
//  {phA's 4 + phB's 4} -> every region drained >=1 phase before its reads
//  (verified incl. prologue/epilogue). Stage-after-read: every region staged
//  >=1 barrier after all waves' last ds_read of it.

#define VM8 asm volatile("s_waitcnt vmcnt(8)" ::: "memory")
#define VM6 asm volatile("s_waitcnt vmcnt(6)" ::: "memory")
#define VM2 asm volatile("s_waitcnt vmcnt(2)" ::: "memory")
#define VM0 asm volatile("s_waitcnt vmcnt(0)" ::: "memory")
#define BAR __builtin_amdgcn_s_barrier()

#define STAGE_A(buf, kt, h) do { \
    const unsigned scl_ = ((((unsigned)(bRow0 + (h) * 64 - ((kt) >> 4))) << 10) + (((unsigned)(kt) & 15u) << 6)) << 1; \
    _Pragma("unroll") for (int q_ = 0; q_ < 2; ++q_) \
      gload_lds16((const char*)xp + (thrA[q_] + scl_), \
                  lds + ((buf) << 15) + ((h) << 14) + (q_ << 13) + (tid << 4)); \
  } while (0)

#define STAGE_B(buf, kt, h) do { \
    const unsigned scl_ = ((((unsigned)(n0 + (h) * 32)) << 12) + ((unsigned)(kt) << 6)) << 1; \
    _Pragma("unroll") for (int q_ = 0; q_ < 2; ++q_) \
      gload_lds16((const char*)Wp + (thrB[q_] + scl_), \
                  lds + 65536 + ((buf) << 15) + ((h) << 14) + (q_ << 13) + (tid << 4)); \
  } while (0)

#define READ_A(dst, buf, h) do { \
    _Pragma("unroll") for (int mi = 0; mi < 4; ++mi) \
    _Pragma("unroll") for (int kk = 0; kk < 2; ++kk) \
      dst[mi][kk] = *(const short8*)(lds + (((buf) << 15) + ((h) << 14)) + aRC[mi][kk]); \
  } while (0)

#define READ_B(dst, buf, h) do { \
    _Pragma("unroll") for (int ni = 0; ni < 2; ++ni) \
    _Pragma("unroll") for (int kk = 0; kk < 2; ++kk) \
      dst[ni][kk] = *(const short8*)(lds + (((buf) << 15) + ((h) << 14)) + bRC[ni][kk]); \
  } while (0)

// one quadrant: 16 MFMA, kk-outer (dep distance 8)
#define MFMAH(mh, nh, A, Bv) do { \
    __builtin_amdgcn_s_setprio(1); \
    _Pragma("unroll") for (int kk = 0; kk < 2; ++kk) \
    _Pragma("unroll") for (int mi = 0; mi < 4; ++mi) \
    _Pragma("unroll") for (int ni = 0; ni < 2; ++ni) \
      acc[(mh) * 4 + mi][(nh) * 2 + ni] = __builtin_amdgcn_mfma_f32_16x16x32_bf16( \
          A[mi][kk], Bv[ni][kk], acc[(mh) * 4 + mi][(nh) * 2 + ni], 0, 0, 0); \
    __builtin_amdgcn_s_setprio(0); \
  } while (0)

__global__ void __launch_bounds__(512, 1)
k_gemm(const unsigned short* __restrict__ xp,
       const unsigned short* __restrict__ Wp,
       const float* __restrict__ bias,
       float* __restrict__ out) {
  __shared__ __attribute__((aligned(16))) unsigned char lds[131072];

  const int tid  = threadIdx.x;
  const int lane = tid & 63;
  const int w    = tid >> 6;       // 0..7
  const int wm   = w >> 2;         // 0..1
  const int wn   = w & 3;          // 0..3

  // bijective XCD swizzle (256 blocks): each XCD gets a contiguous
  // 8-mtile x 4-ntile chunk -> A fetched once per XCD.
  const int bid = blockIdx.x;
  const int swz = (bid & 7) * 32 + (bid >> 3);
  const int m0 = (swz >> 2) * BM;
  const int n0 = (swz & 3) * BN;
  const int b  = m0 >> 11;
  const int l0 = m0 & 2047;
  const int bRow0 = b * LPAD + l0 + 3;           // SGPR

  // ---- staging geometry: per-thread u32 BYTE offsets (invariant part) ----
  const int sr0 = tid >> 3;                                  // 0..63
  const unsigned clog = ((unsigned)((tid & 7) ^ (sr0 & 7))) << 3;  // elem offset
  unsigned thrA[2], thrB[2];
  const unsigned nb0 = (((unsigned)sr0 >> 5) << 6) + ((unsigned)sr0 & 31);
#pragma unroll
  for (int q = 0; q < 2; ++q) {
    thrA[q] = ((((unsigned)(sr0 + q * 128)) << 10) + clog) << 1;   // bytes
    thrB[q] = (((nb0 + q * 128u) << 12) + clog) << 1;              // bytes
  }

  // ---- ds_read addresses: precomputed VGPRs, region via offset-imm ----
  int aRC[4][2], bRC[2][2];
  {
    int colByte[2];
#pragma unroll
    for (int kk = 0; kk < 2; ++kk)
      colByte[kk] = (kk * 64 + ((lane >> 4) << 4)) ^ ((lane & 7) << 4);
#pragma unroll
    for (int mi = 0; mi < 4; ++mi)
#pragma unroll
      for (int kk = 0; kk < 2; ++kk)
        aRC[mi][kk] = ((wm * 64 + mi * 16 + (lane & 15)) << 7) + colByte[kk];
#pragma unroll
    for (int ni = 0; ni < 2; ++ni)
#pragma unroll
      for (int kk = 0; kk < 2; ++kk)
        bRC[ni][kk] = 65536 + ((wn * 32 + ni * 16 + (lane & 15)) << 7) + colByte[kk];
  }

  f32x4 acc[8][4] = {};
  short8 a0[4][2], a1[4][2], bX[2][2], bY[2][2];

  // ---- prologue ----
  STAGE_A(0, 0, 0);                  // tile0 A0   (g1,g2)
  STAGE_B(0, 0, 0);                  // tile0 B0   (g3,g4)
  STAGE_B(0, 0, 1);                  // tile0 B1   (g5,g6)
  STAGE_A(0, 0, 1);                  // tile0 A1   (g7,g8)
  STAGE_A(1, 1, 0);                  // tile1 A0   (g9,g10)
  STAGE_B(1, 1, 0);                  // tile1 B0   (g11,g12)
  VM6;                               // drain tile0 A0,B0,B1
  BAR;
  READ_A(a0, 0, 0); READ_B(bX, 0, 0); READ_B(bY, 0, 1);   // tile0 operands
  STAGE_B(1, 1, 1);                  // tile1 B1
  STAGE_A(1, 1, 1);                  // tile1 A1
  VM8;                               // drain tile0 A1 (read next phase)
  BAR;

  // ---- main loop: 31 iters, tiles T=2it (buf0), T+1 (buf1) ----
#pragma unroll 1
  for (int it = 0; it < 31; ++it) {
    const int T = it * 2;
    // phA(T)
    READ_A(a1, 0, 1);                          // A1(T)  (a1 dead here)
    STAGE_A(0, T + 2, 0); STAGE_B(0, T + 2, 0);
    MFMAH(0, 0, a0, bX);
    MFMAH(0, 1, a0, bY);
    VM6; BAR;
    // phB(T)
    READ_A(a0, 1, 0);                          // A0(T+1)  (a0 dead here)
    STAGE_B(0, T + 2, 1); STAGE_A(0, T + 2, 1);
    MFMAH(1, 0, a1, bX);
    READ_B(bX, 1, 0);                          // B0(T+1)  (WAR after Q10)
    MFMAH(1, 1, a1, bY);
    READ_B(bY, 1, 1);                          // B1(T+1)  (WAR after Q11)
    VM8; BAR;
    // phA(T+1)
    READ_A(a1, 1, 1);                          // A1(T+1)
    STAGE_A(1, T + 3, 0); STAGE_B(1, T + 3, 0);
    MFMAH(0, 0, a0, bX);
    MFMAH(0, 1, a0, bY);
    VM6; BAR;
    // phB(T+1)
    READ_A(a0, 0, 0);                          // A0(T+2)
    STAGE_B(1, T + 3, 1); STAGE_A(1, T + 3, 1);
    MFMAH(1, 0, a1, bX);
    READ_B(bX, 0, 0);                          // B0(T+2)
    MFMAH(1, 1, a1, bY);
    READ_B(bY, 0, 1);                          // B1(T+2)
    VM8; BAR;
  }

  // ---- epilogue: tiles 62 (buf0), 63 (buf1); all staged in-loop ----
  // phA(62)
  READ_A(a1, 0, 1);
  MFMAH(0, 0, a0, bX);
  MFMAH(0, 1, a0, bY);
  VM2; BAR;                          // drain A0,B0,B1(63); leaves A1(63)
  // phB(62)
  READ_A(a0, 1, 0);
  MFMAH(1, 0, a1, bX);
  READ_B(bX, 1, 0);
  MFMAH(1, 1, a1, bY);
  READ_B(bY, 1, 1);
  VM0; BAR;                          // drain A1(63)
  // phA(63)
  READ_A(a1, 1, 1);
  MFMAH(0, 0, a0, bX);
  MFMAH(0, 1, a0, bY);
  // phB(63)
  MFMAH(1, 0, a1, bX);
  MFMAH(1, 1, a1, bY);

  // ---- C write: col = lane&15, row = (lane>>4)*4 + reg ----
#pragma unroll
  for (int nig = 0; nig < 4; ++nig) {
    const int col = n0 + wn * 64 + nig * 16 + (lane & 15);
    const float bv = bias[col];
#pragma unroll
    for (int mig = 0; mig < 8; ++mig) {
      const int row0 = m0 + wm * 128 + mig * 16 + ((lane >> 4) << 2);
#pragma unroll
      for (int t2 = 0; t2 < 4; ++t2)
        out[(size_t)(row0 + t2) * Dq + col] = acc[mig][nig][t2] + bv;
    }
  }
}

// ---- slow-but-correct fallback if workspace is too small ----
__global__ void k_naive(const float* __restrict__ x, const float* __restrict__ W,
                        const float* __restrict__ bias, float* __restrict__ out) {
  size_t g = (size_t)blockIdx.x * blockDim.x + threadIdx.x;
  const size_t total = (size_t)Bq * Lq * Dq;
  if (g >= total) return;
  int d = (int)(g & 1023);
  int l = (int)((g >> 10) & 2047);
  int b = (int)(g >> 21);
  float s = bias[d];
  for (int i = 0; i < Pq; ++i) {
    if (l - i < 0) continue;
    const float* xr = x + ((size_t)b * Lq + (l - i)) * Dq;
    const float* wr = W + (size_t)d * Kq + i;
    float accv = 0.f;
    for (int dp = 0; dp < Dq; ++dp) accv += xr[dp] * wr[(size_t)dp * 4];
    s += accv;
  }
  out[g] = s;
}

extern "C" void kernel_launch(void* const* d_in, const int* in_sizes, int n_in,
                              void* d_out, int out_size, void* d_ws, size_t ws_size,
                              hipStream_t stream) {
  const float* x    = (const float*)d_in[0];
  const float* W    = (const float*)d_in[1];
  const float* bias = (const float*)d_in[2];
  float* out = (float*)d_out;

  const size_t WP_BYTES = (size_t)Dq * Kq * sizeof(unsigned short);        // 8 MiB
  const size_t XP_BYTES = (size_t)Bq * LPAD * Dq * sizeof(unsigned short); // ~33.7 MB

  if (ws_size < WP_BYTES + XP_BYTES) {
    const size_t total = (size_t)Bq * Lq * Dq;
    k_naive<<<(unsigned)((total + 255) / 256), 256, 0, stream>>>(x, W, bias, out);
    return;
  }

  unsigned short* Wp = (unsigned short*)d_ws;
  unsigned short* xp = (unsigned short*)((char*)d_ws + WP_BYTES);

  k_prep<<<10272, 256, 0, stream>>>(x, W, xp, Wp);
  k_gemm<<<dim3((Bq * Lq / BM) * (Dq / BN)), 512, 0, stream>>>(xp, Wp, bias, out);
}

// Round 12
// 159.480 us; speedup vs baseline: 2.2455x; 1.2819x over previous
//
#include <hip/hip_runtime.h>
#include <hip/hip_bf16.h>
#include <stdint.h>

// Problem constants
#define Bq 8
#define Lq 2048
#define Dq 1024
#define Pq 4
#define Kq 4096          // D*P
#define LPAD 2056        // 3 zero rows + 2048 data + 5 slack, per batch
// GEMM tiling: 256x256, BK=64, 8 waves, SKEWED WAVE-GROUP pipeline:
// group E (waves 0-3) and O (waves 4-7) alternate {MFMA tile t} / {read tile t}
// per phase -> MFMA pipe and LDS unit busy concurrently, 1 frag set per wave.
#define BM 256
#define BN 256
#define BK 64

typedef __attribute__((ext_vector_type(8))) short short8;   // 8 bf16 (4 VGPRs)
typedef __attribute__((ext_vector_type(4))) float f32x4;

__device__ __forceinline__ unsigned short f2bf(float f) {
  unsigned u = __float_as_uint(f);
  u += 0x7FFFu + ((u >> 16) & 1u);   // round-to-nearest-even
  return (unsigned short)(u >> 16);
}

__device__ __forceinline__ void gload_lds16(const void* g, void* l) {
  __builtin_amdgcn_global_load_lds(
      (const __attribute__((address_space(1))) void*)g,
      (__attribute__((address_space(3))) void*)l, 16, 0, 0);
}

// ---- merged prep: blocks [0,8224) do xp, blocks [8224,10272) do Wp ----
__global__ void k_prep(const float* __restrict__ x, const float* __restrict__ W,
                       unsigned short* __restrict__ xp, unsigned short* __restrict__ Wp) {
  if (blockIdx.x < 8224u) {
    unsigned g = blockIdx.x * blockDim.x + threadIdx.x;
    unsigned base = g * 8;
    const unsigned total = (unsigned)Bq * LPAD * Dq;
    if (base >= total) return;
    unsigned t = base >> 10;            // b*LPAD + r
    unsigned b = t / LPAD;
    unsigned r = t - b * LPAD;
    unsigned d = base & 1023;
    short8 o;
    if (r >= 3 && r < 3 + Lq) {
      const float* s = x + ((size_t)b * Lq + (r - 3)) * Dq + d;
      float4 v0 = *(const float4*)(s);
      float4 v1 = *(const float4*)(s + 4);
      o[0] = (short)f2bf(v0.x); o[1] = (short)f2bf(v0.y);
      o[2] = (short)f2bf(v0.z); o[3] = (short)f2bf(v0.w);
      o[4] = (short)f2bf(v1.x); o[5] = (short)f2bf(v1.y);
      o[6] = (short)f2bf(v1.z); o[7] = (short)f2bf(v1.w);
    } else {
      o = (short8)0;
    }
    *(short8*)(xp + base) = o;
  } else {
    unsigned g = (blockIdx.x - 8224u) * blockDim.x + threadIdx.x;
    unsigned base = g * 8;
    unsigned d = base >> 12;
    unsigned rem = base & 4095;
    unsigned dp = rem >> 2;                               // even
    const float4* src = (const float4*)(W + base);
    float4 v0 = src[0];
    float4 v1 = src[1];
    float a0[4] = {v0.x, v0.y, v0.z, v0.w};
    float a1[4] = {v1.x, v1.y, v1.z, v1.w};
#pragma unroll
    for (int i = 0; i < 4; ++i) {
      unsigned packed = (unsigned)f2bf(a0[i]) | ((unsigned)f2bf(a1[i]) << 16);
      *(unsigned*)(Wp + (size_t)d * 4096 + (size_t)i * 1024 + dp) = packed;
    }
  }
}

// ====== 256x256 GEMM, skewed wave-group pipeline ======
// C[m][n] = sum_k A[m][k]*Wp[n][k] + bias[n],  A[m][i*1024+d'] = xp[b][l+3-i][d']
// LDS (128 KiB): A in [0,64K): [buf:32K][h:16K]; B in [64K,128K): same.
//   byte within 128B row: SWIZZLED  phys_c = log_c ^ ((r&7)<<4)
// Waves 0-3 = group E (wm=0, rows 0..127), waves 4-7 = O (wm=1, rows 128..255);
// one E + one O wave per SIMD. Phases alternate:
//   even phase: E reads tile k (24 ds_read_b128) ; O MFMAs tile k-1 (64 MFMA)
//               both issue stage gloads for tile k+1 (E: A 8, O: B 8)
//   odd  phase: E MFMAs tile k ; O reads tile k ; VM0 (drains ~1-phase-old stages)
// Per-wave frags = ONE tile set (96 VGPR), written in read phase, consumed in
// MFMA phase -> clean disjoint liveness, no extra sets. Stage-vs-read hazards:
// tile k+1 staged into buf (k+1)&1 whose last reader (tile k-1, group O) was
// 2 phases earlier; VM0+barrier publish before first read.  sched_barrier(0xF)
// after each barrier keeps DS/VMEM inside their phase (ALU/MFMA may cross).

#define VM0 asm volatile("s_waitcnt vmcnt(0)" ::: "memory")
#define BAR __builtin_amdgcn_s_barrier()
#define SBF __builtin_amdgcn_sched_barrier(0xF)

// E stages full A tile (2h x 4q = 8 gloads, 256 threads cover 16KB/region);
// O stages full B tile likewise.
#define STAGE_T(buf, kt) do { \
    if (gE) { \
      _Pragma("unroll") for (int h_ = 0; h_ < 2; ++h_) \
      _Pragma("unroll") for (int q_ = 0; q_ < 4; ++q_) { \
        const unsigned scl_ = (((unsigned)(bRow0 + ((q_ >> 1) * 128 + (q_ & 1) * 32 + h_ * 64) - ((kt) >> 4))) << 11) + (((unsigned)(kt) & 15u) << 7); \
        gload_lds16((const char*)xp + (thrS + scl_), \
                    lds + (((buf) << 15) + (h_ << 14) + (q_ << 12)) + (tt << 4)); \
      } \
    } else { \
      _Pragma("unroll") for (int h_ = 0; h_ < 2; ++h_) \
      _Pragma("unroll") for (int q_ = 0; q_ < 4; ++q_) { \
        const unsigned scl_ = (((unsigned)(n0 + q_ * 64 + h_ * 32)) << 13) + ((unsigned)(kt) << 7); \
        gload_lds16((const char*)Wp + (thrS + scl_), \
                    lds + 65536 + (((buf) << 15) + (h_ << 14) + (q_ << 12)) + (tt << 4)); \
      } \
    } \
  } while (0)

#define RD_A(dst, buf, h) do { \
    _Pragma("unroll") for (int mi = 0; mi < 4; ++mi) \
    _Pragma("unroll") for (int kk = 0; kk < 2; ++kk) \
      dst[mi][kk] = *(const short8*)(lds + aK[kk] + (((buf) << 15) + ((h) << 14) + (mi << 11))); \
  } while (0)

#define RD_B(dst, buf, h) do { \
    _Pragma("unroll") for (int ni = 0; ni < 2; ++ni) \
    _Pragma("unroll") for (int kk = 0; kk < 2; ++kk) \
      dst[ni][kk] = *(const short8*)(lds + bK[kk] + (((buf) << 15) + ((h) << 14) + (ni << 11))); \
  } while (0)

#define READ_TILE(buf) do { \
    RD_A(fa0, buf, 0); RD_A(fa1, buf, 1); RD_B(bX, buf, 0); RD_B(bY, buf, 1); \
  } while (0)

#define MFMAH(mh, nh, A, Bv) do { \
    _Pragma("unroll") for (int kk = 0; kk < 2; ++kk) \
    _Pragma("unroll") for (int mi = 0; mi < 4; ++mi) \
    _Pragma("unroll") for (int ni = 0; ni < 2; ++ni) \
      acc[(mh) * 4 + mi][(nh) * 2 + ni] = __builtin_amdgcn_mfma_f32_16x16x32_bf16( \
          A[mi][kk], Bv[ni][kk], acc[(mh) * 4 + mi][(nh) * 2 + ni], 0, 0, 0); \
  } while (0)

#define MFMA_TILE() do { \
    __builtin_amdgcn_s_setprio(1); \
    MFMAH(0, 0, fa0, bX); MFMAH(0, 1, fa0, bY); \
    MFMAH(1, 0, fa1, bX); MFMAH(1, 1, fa1, bY); \
    __builtin_amdgcn_s_setprio(0); \
  } while (0)

__global__ void __launch_bounds__(512, 1)
k_gemm(const unsigned short* __restrict__ xp,
       const unsigned short* __restrict__ Wp,
       const float* __restrict__ bias,
       float* __restrict__ out) {
  __shared__ __attribute__((aligned(16))) unsigned char lds[131072];

  const int tid  = threadIdx.x;
  const int lane = tid & 63;
  const int w    = tid >> 6;       // 0..7
  const int wm   = w >> 2;         // 0 = group E, 1 = group O
  const int wn   = w & 3;          // 0..3
  const bool gE  = (wm == 0);

  // bijective XCD swizzle (256 blocks): each XCD gets a contiguous
  // 8-mtile x 4-ntile chunk -> A fetched once per XCD.
  const int bid = blockIdx.x;
  const int swz = (bid & 7) * 32 + (bid >> 3);
  const int m0 = (swz >> 2) * BM;
  const int n0 = (swz & 3) * BN;
  const int b  = m0 >> 11;
  const int l0 = m0 & 2047;
  const int bRow0 = b * LPAD + l0 + 3;           // SGPR (wave-uniform)

  // ---- staging per-thread invariant (shared VGPR across groups) ----
  const int tt = tid & 255;                      // 0..255 within group
  const int sr = tt >> 3;                        // 0..31 (row within 32-row chunk)
  const unsigned clogB = ((unsigned)((tid & 7) ^ (sr & 7))) << 4;   // swizzled col bytes
  const unsigned thrS = gE ? ((((unsigned)sr) << 11) + clogB)       // A: row*2048 B
                           : ((((unsigned)sr) << 13) + clogB);      // B: row*8192 B

  // ---- ds_read base addresses (4 VGPRs; buf/h/mi/ni via offset immediates) ----
  unsigned aK[2], bK[2];
  {
    const int slot = (lane >> 4) << 4;
    const int sw = (lane & 7) << 4;
#pragma unroll
    for (int kk = 0; kk < 2; ++kk) {
      const int cb = (kk * 64 + slot) ^ sw;
      aK[kk] = (unsigned)((wm << 13) + ((lane & 15) << 7) + cb);
      bK[kk] = (unsigned)(65536 + ((wn * 32 + (lane & 15)) << 7) + cb);
    }
  }

  f32x4 acc[8][4] = {};
  short8 fa0[4][2], fa1[4][2], bX[2][2], bY[2][2];

  // ---- prologue: stage tile0; ph0: E reads t0, both stage t1; ph1 ----
  STAGE_T(0, 0);                     // E: A(t0), O: B(t0)
  VM0; BAR; SBF;
  if (gE) { READ_TILE(0); }          // ph0: E reads t0; O idle
  STAGE_T(1, 1);
  BAR; SBF;
  if (gE) { MFMA_TILE(); } else { READ_TILE(0); }   // ph1
  VM0; BAR; SBF;

  // ---- main loop: 31 iters; tiles U=2it+1 (buf1), V=2it+2 (buf0) ----
#pragma unroll 1
  for (int it = 0; it < 31; ++it) {
    const int V = 2 * it + 2;
    // phE1: E read U(buf1); O MFMA T=2it; stage V(buf0)
    STAGE_T(0, V);
    if (gE) { READ_TILE(1); } else { MFMA_TILE(); }
    BAR; SBF;
    // phO1: E MFMA U; O read U(buf1)
    if (gE) { MFMA_TILE(); } else { READ_TILE(1); }
    VM0; BAR; SBF;
    // phE2: E read V(buf0); O MFMA U; stage V+1(buf1)
    STAGE_T(1, V + 1);
    if (gE) { READ_TILE(0); } else { MFMA_TILE(); }
    BAR; SBF;
    // phO2: E MFMA V; O read V(buf0)
    if (gE) { MFMA_TILE(); } else { READ_TILE(0); }
    VM0; BAR; SBF;
  }

  // ---- epilogue: tile 63 (buf1) ----
  if (gE) { READ_TILE(1); } else { MFMA_TILE(); }   // E rd t63; O MFMA t62
  BAR; SBF;
  if (gE) { MFMA_TILE(); } else { READ_TILE(1); }   // E MFMA t63; O rd t63
  BAR; SBF;
  if (!gE) { MFMA_TILE(); }                          // O MFMA t63

  // ---- C write: col = lane&15, row = (lane>>4)*4 + reg ----
#pragma unroll
  for (int nig = 0; nig < 4; ++nig) {
    const int col = n0 + wn * 64 + nig * 16 + (lane & 15);
    const float bv = bias[col];
#pragma unroll
    for (int mig = 0; mig < 8; ++mig) {
      const int row0 = m0 + wm * 128 + mig * 16 + ((lane >> 4) << 2);
#pragma unroll
      for (int t2 = 0; t2 < 4; ++t2)
        out[(size_t)(row0 + t2) * Dq + col] = acc[mig][nig][t2] + bv;
    }
  }
}

// ---- slow-but-correct fallback if workspace is too small ----
__global__ void k_naive(const float* __restrict__ x, const float* __restrict__ W,
                        const float* __restrict__ bias, float* __restrict__ out) {
  size_t g = (size_t)blockIdx.x * blockDim.x + threadIdx.x;
  const size_t total = (size_t)Bq * Lq * Dq;
  if (g >= total) return;
  int d = (int)(g & 1023);
  int l = (int)((g >> 10) & 2047);
  int b = (int)(g >> 21);
  float s = bias[d];
  for (int i = 0; i < Pq; ++i) {
    if (l - i < 0) continue;
    const float* xr = x + ((size_t)b * Lq + (l - i)) * Dq;
    const float* wr = W + (size_t)d * Kq + i;
    float accv = 0.f;
    for (int dp = 0; dp < Dq; ++dp) accv += xr[dp] * wr[(size_t)dp * 4];
    s += accv;
  }
  out[g] = s;
}

extern "C" void kernel_launch(void* const* d_in, const int* in_sizes, int n_in,
                              void* d_out, int out_size, void* d_ws, size_t ws_size,
                              hipStream_t stream) {
  const float* x    = (const float*)d_in[0];
  const float* W    = (const float*)d_in[1];
  const float* bias = (const float*)d_in[2];
  float* out = (float*)d_out;

  const size_t WP_BYTES = (size_t)Dq * Kq * sizeof(unsigned short);        // 8 MiB
  const size_t XP_BYTES = (size_t)Bq * LPAD * Dq * sizeof(unsigned short); // ~33.7 MB

  if (ws_size < WP_BYTES + XP_BYTES) {
    const size_t total = (size_t)Bq * Lq * Dq;
    k_naive<<<(unsigned)((total + 255) / 256), 256, 0, stream>>>(x, W, bias, out);
    return;
  }

  unsigned short* Wp = (unsigned short*)d_ws;
  unsigned short* xp = (unsigned short*)((char*)d_ws + WP_BYTES);

  k_prep<<<10272, 256, 0, stream>>>(x, W, xp, Wp);
  k_gemm<<<dim3((Bq * Lq / BM) * (Dq / BN)), 512, 0, stream>>>(xp, Wp, bias, out);
}